// Round 5
// baseline (129.640 us; speedup 1.0000x reference)
//
#include <hip/hip_runtime.h>
#include <float.h>

#define BATCH 32
#define C_IN 16
#define C_OUT 32
#define NTOK 2048
#define KNN 3

#define RN 4                  // n-columns per thread
#define NCHUNK (256 * RN)     // 1024 n per block

// Kernel 1: transpose x (B,C,N) -> xT (B,N,C), sq[b][n] = sum_c x^2 (rounded mul, seq add)
__global__ void __launch_bounds__(256) transpose_sq_kernel(
    const float* __restrict__ x, float* __restrict__ xT, float* __restrict__ sq)
{
    const int n = blockIdx.x * 256 + threadIdx.x;
    const int b = blockIdx.y;
    const float* xb = x + (size_t)b * C_IN * NTOK;

    float v[C_IN];
#pragma unroll
    for (int c = 0; c < C_IN; ++c) v[c] = xb[(size_t)c * NTOK + n];

    float acc = 0.0f;
#pragma unroll
    for (int c = 0; c < C_IN; ++c) acc = __fadd_rn(acc, __fmul_rn(v[c], v[c]));
    sq[(size_t)b * NTOK + n] = acc;

    float4* dst = (float4*)(xT + ((size_t)b * NTOK + n) * C_IN);
#pragma unroll
    for (int j = 0; j < 4; ++j)
        dst[j] = make_float4(v[4 * j + 0], v[4 * j + 1], v[4 * j + 2], v[4 * j + 3]);
}

// Kernel 2: block = 256 threads, RN=4 n's each (n-chunk 1024); scans one SEG-long
// m-segment (x-tile AND sq-tile staged in LDS). Chunked m-loop: 4 m's per chunk so
// all ds_read offsets are immediates and sq comes as one broadcast b128 per chunk.
template<int SEG>
__global__ void __launch_bounds__(256, 4) knn_partial_kernel(
    const float* __restrict__ xT, const float* __restrict__ sq,
    float* __restrict__ part)
{
    __shared__ float lds_x[SEG * C_IN];   // SEG=128 -> 8 KB
    __shared__ float lds_sq[SEG];         // 512 B

    const int tid = threadIdx.x;
    const int b = blockIdx.y;
    const int z = blockIdx.z;
    const int nbase = blockIdx.x * NCHUNK;
    const int mbase = z * SEG;

    const float* xb  = xT + (size_t)b * NTOK * C_IN;
    const float* sqb = sq + (size_t)b * NTOK;

    // stage m-tile + sq-tile (coalesced float4)
    {
        const float4* gsrc = (const float4*)(xb + (size_t)mbase * C_IN);
        float4* ldst = (float4*)lds_x;
#pragma unroll
        for (int j = 0; j < SEG / 64; ++j)
            ldst[tid + 256 * j] = gsrc[tid + 256 * j];
        if (tid < SEG / 4)
            ((float4*)lds_sq)[tid] = ((const float4*)(sqb + mbase))[tid];
    }

    // own columns
    float xn[RN][C_IN];
    float sqn[RN];
#pragma unroll
    for (int q = 0; q < RN; ++q) {
        const int n = nbase + q * 256 + tid;
        const float4* src = (const float4*)(xb + (size_t)n * C_IN);
#pragma unroll
        for (int j = 0; j < 4; ++j) {
            float4 t = src[j];
            xn[q][4 * j + 0] = t.x; xn[q][4 * j + 1] = t.y;
            xn[q][4 * j + 2] = t.z; xn[q][4 * j + 3] = t.w;
        }
        sqn[q] = sqb[n];
    }
    __syncthreads();

    float d0[RN], d1[RN], d2[RN];
    int   i0[RN], i1[RN], i2[RN];
#pragma unroll
    for (int q = 0; q < RN; ++q) {
        d0[q] = FLT_MAX; d1[q] = FLT_MAX; d2[q] = FLT_MAX;
        i0[q] = 0; i1[q] = 0; i2[q] = 0;
    }

    // chunked scan: 4 m's per chunk, inner fully unrolled (immediate ds offsets)
    for (int mc = 0; mc < SEG; mc += 4) {
        const float4 sq4 = *((const float4*)(lds_sq + mc));   // broadcast b128
        const float sqm[4] = { sq4.x, sq4.y, sq4.z, sq4.w };
        const float* lxc = lds_x + mc * C_IN;

#pragma unroll
        for (int u = 0; u < 4; ++u) {
            const float4* r4 = (const float4*)(lxc + u * C_IN);
            const float4 A0 = r4[0], A1 = r4[1], A2 = r4[2], A3 = r4[3];
            const int m = mbase + mc + u;

#pragma unroll
            for (int q = 0; q < RN; ++q) {
                // sequential c-chain, bitexact to the fp32 reference recipe
                float g = 0.0f;
                g = __fmaf_rn(xn[q][0],  A0.x, g); g = __fmaf_rn(xn[q][1],  A0.y, g);
                g = __fmaf_rn(xn[q][2],  A0.z, g); g = __fmaf_rn(xn[q][3],  A0.w, g);
                g = __fmaf_rn(xn[q][4],  A1.x, g); g = __fmaf_rn(xn[q][5],  A1.y, g);
                g = __fmaf_rn(xn[q][6],  A1.z, g); g = __fmaf_rn(xn[q][7],  A1.w, g);
                g = __fmaf_rn(xn[q][8],  A2.x, g); g = __fmaf_rn(xn[q][9],  A2.y, g);
                g = __fmaf_rn(xn[q][10], A2.z, g); g = __fmaf_rn(xn[q][11], A2.w, g);
                g = __fmaf_rn(xn[q][12], A3.x, g); g = __fmaf_rn(xn[q][13], A3.y, g);
                g = __fmaf_rn(xn[q][14], A3.z, g); g = __fmaf_rn(xn[q][15], A3.w, g);

                // (sqn - 2g) + sqm ; fma(-2,g,sqn) bitexact to sub(sqn, mul(2,g))
                const float d = __fadd_rn(__fmaf_rn(-2.0f, g, sqn[q]), sqm[u]);

                // branchless tie-exact top-3 insert (strict <: earlier index wins)
                const bool c0 = d < d0[q], c1 = d < d1[q], c2 = d < d2[q];
                const float od0 = d0[q], od1 = d1[q];
                const int   oi0 = i0[q], oi1 = i1[q];
                d0[q] = fminf(d, d0[q]);
                d1[q] = __builtin_amdgcn_fmed3f(d, od0, d1[q]);
                d2[q] = __builtin_amdgcn_fmed3f(d, od1, d2[q]);
                i0[q] = c0 ? m : i0[q];
                i1[q] = c0 ? oi0 : (c1 ? m : i1[q]);
                i2[q] = c1 ? oi1 : (c2 ? m : i2[q]);
            }
        }
    }

    // write partial lists: part[((k*Z + z)*BATCH + b)*NTOK + n], Z = NTOK/SEG
    const size_t stride = (size_t)(NTOK / SEG) * BATCH * NTOK;
#pragma unroll
    for (int q = 0; q < RN; ++q) {
        const int n = nbase + q * 256 + tid;
        const size_t base = ((size_t)z * BATCH + b) * NTOK + n;
        part[base + 0 * stride] = d0[q];
        part[base + 1 * stride] = d1[q];
        part[base + 2 * stride] = d2[q];
        part[base + 3 * stride] = __int_as_float(i0[q]);
        part[base + 4 * stride] = __int_as_float(i1[q]);
        part[base + 5 * stride] = __int_as_float(i2[q]);
    }
}

// Kernel 3: merge Z partials per n (ascending z = ascending m-range, strict <
// keeps earlier index), gather 3 neighbor columns, conv epilogue.
template<int Z>
__global__ void __launch_bounds__(256) merge_conv_kernel(
    const float* __restrict__ xT, const float* __restrict__ part,
    const float* __restrict__ W, const float* __restrict__ bias,
    float* __restrict__ out)
{
    const int n = blockIdx.x * 256 + threadIdx.x;
    const int b = blockIdx.y;

    float D0 = FLT_MAX, D1 = FLT_MAX, D2 = FLT_MAX;
    int   I0 = 0,       I1 = 0,       I2 = 0;

    const size_t stride = (size_t)Z * BATCH * NTOK;
#pragma unroll
    for (int z = 0; z < Z; ++z) {
        const size_t base = ((size_t)z * BATCH + b) * NTOK + n;
#pragma unroll
        for (int k = 0; k < KNN; ++k) {
            const float dc = part[base + (size_t)k * stride];
            const int   ic = __float_as_int(part[base + (size_t)(3 + k) * stride]);
            const bool c0 = dc < D0, c1 = dc < D1, c2 = dc < D2;
            const float oD0 = D0, oD1 = D1;
            const int   oI0 = I0, oI1 = I1;
            D0 = fminf(dc, D0);
            D1 = __builtin_amdgcn_fmed3f(dc, oD0, D1);
            D2 = __builtin_amdgcn_fmed3f(dc, oD1, D2);
            I0 = c0 ? ic : I0;
            I1 = c0 ? oI0 : (c1 ? ic : I1);
            I2 = c1 ? oI1 : (c2 ? ic : I2);
        }
    }

    const float* xb = xT + (size_t)b * NTOK * C_IN;
    float xg[KNN][C_IN];
    const int idx[KNN] = { I0, I1, I2 };
#pragma unroll
    for (int k = 0; k < KNN; ++k) {
        const float4* src = (const float4*)(xb + (size_t)idx[k] * C_IN);
#pragma unroll
        for (int j = 0; j < 4; ++j) {
            float4 t = src[j];
            xg[k][4 * j + 0] = t.x; xg[k][4 * j + 1] = t.y;
            xg[k][4 * j + 2] = t.z; xg[k][4 * j + 3] = t.w;
        }
    }

#pragma unroll
    for (int o = 0; o < C_OUT; ++o) {
        float acc = bias[o];
#pragma unroll
        for (int c = 0; c < C_IN; ++c) {
#pragma unroll
            for (int k = 0; k < KNN; ++k)
                acc = __fmaf_rn(W[(o * C_IN + c) * KNN + k], xg[k][c], acc);
        }
        out[((size_t)b * C_OUT + o) * NTOK + n] = acc;
    }
}

extern "C" void kernel_launch(void* const* d_in, const int* in_sizes, int n_in,
                              void* d_out, int out_size, void* d_ws, size_t ws_size,
                              hipStream_t stream) {
    const float* x    = (const float*)d_in[0];
    const float* W    = (const float*)d_in[1];
    const float* bias = (const float*)d_in[2];
    float* out = (float*)d_out;

    float* xT   = (float*)d_ws;                                  // 4 MB
    float* sq   = xT + (size_t)BATCH * NTOK * C_IN;              // 256 KB
    float* part = sq + (size_t)BATCH * NTOK;

    const size_t base_bytes = ((size_t)BATCH * NTOK * C_IN + (size_t)BATCH * NTOK) * 4;
    const size_t part16     = 6ull * 16 * BATCH * NTOK * 4;      // 25.2 MB

    dim3 grid1(NTOK / 256, BATCH);
    transpose_sq_kernel<<<grid1, 256, 0, stream>>>(x, xT, sq);

    if (ws_size >= base_bytes + part16) {
        // Z=16: SEG=128 -> 1024 blocks -> 4 waves/SIMD
        dim3 grid2(NTOK / NCHUNK, BATCH, 16);
        knn_partial_kernel<128><<<grid2, 256, 0, stream>>>(xT, sq, part);
        dim3 grid3(NTOK / 256, BATCH);
        merge_conv_kernel<16><<<grid3, 256, 0, stream>>>(xT, part, W, bias, out);
    } else {
        // Z=8: SEG=256 -> 512 blocks (17 MB ws)
        dim3 grid2(NTOK / NCHUNK, BATCH, 8);
        knn_partial_kernel<256><<<grid2, 256, 0, stream>>>(xT, sq, part);
        dim3 grid3(NTOK / 256, BATCH);
        merge_conv_kernel<8><<<grid3, 256, 0, stream>>>(xT, part, W, bias, out);
    }
}